// Round 1
// baseline (192.473 us; speedup 1.0000x reference)
//
#include <hip/hip_runtime.h>

typedef __bf16 bf16;
typedef bf16 bf16x8 __attribute__((ext_vector_type(8)));
typedef float f32x4 __attribute__((ext_vector_type(4)));

#define MFMA16(a,b,c) __builtin_amdgcn_mfma_f32_16x16x32_bf16(a,b,c,0,0,0)

#define HW 16384   // 128*128
#define NQ 4096    // positions per window
#define CH 64

// ---- workspace layout (bytes) ----
constexpr size_t OFF_RED  = 0;                                    // 2048 (256 sums + 256 sumsq)
constexpr size_t OFF_SCAL = 2048;                                 // mean, rstd
constexpr size_t OFF_Q    = 4096;                                 // bf16 (4,4096,64)  2 MB
constexpr size_t OFF_VT   = OFF_Q  + (size_t)4*NQ*CH*2;           // bf16 (4,64,4096)  2 MB
constexpr size_t OFF_OP   = OFF_VT + (size_t)4*NQ*CH*2;           // fp32 (2,16384,64) 8 MB
constexpr size_t OFF_LP   = OFF_OP + (size_t)2*16384*64*4;        // fp32 (2,16384)
constexpr size_t OFF_AT   = OFF_LP + (size_t)2*16384*4;           // fp32 CHW attn_raw 4 MB
constexpr size_t OFF_T    = OFF_OP;                               // bf16 HWC (reuse Opart)
constexpr size_t OFF_T2   = OFF_OP + (size_t)2097152;
constexpr size_t OFF_T3   = OFF_OP + (size_t)4194304;
constexpr size_t OFF_W1   = OFF_AT + (size_t)4194304;             // bf16 (9,64,64)
constexpr size_t OFF_W2   = OFF_W1 + 73728;
constexpr size_t OFF_W3   = OFF_W2 + 73728;                       // bf16 (64,64)

__device__ inline float exp_small(float t) {
    // e^t for t in [-0.05, 0.30]; deg-5 Taylor, max rel err ~4e-7
    return 1.f + t*(1.f + t*(0.5f + t*(0.16666667f + t*(0.041666668f + t*0.0083333338f))));
}

// ---------- K0: weight prep (transpose to [tap][co][ci], bf16) ----------
__global__ void k_prep_w(const float* __restrict__ w1, const float* __restrict__ w2,
                         const float* __restrict__ w3,
                         bf16* __restrict__ W1, bf16* __restrict__ W2, bf16* __restrict__ W3) {
    int g = blockIdx.x * 256 + threadIdx.x;
    if (g < 36864) {
        int tap = g >> 12, co = (g >> 6) & 63, ci = g & 63;
        W1[g] = (bf16)w1[(co*64 + ci)*9 + tap];
    } else if (g < 73728) {
        int d = g - 36864;
        int tap = d >> 12, co = (d >> 6) & 63, ci = d & 63;
        W2[d] = (bf16)w2[(co*64 + ci)*9 + tap];
    } else if (g < 77824) {
        int d = g - 73728;
        W3[d] = (bf16)w3[d];
    }
}

// ---------- K1: partial reduction for layernorm ----------
__global__ __launch_bounds__(256) void k_red1(const float* __restrict__ x, float* __restrict__ red) {
    int t = threadIdx.x, bx = blockIdx.x;
    float s = 0.f, ss = 0.f;
    const float* base = x + (size_t)bx*4096;
    #pragma unroll
    for (int k = 0; k < 4; ++k) {
        float4 v = *(const float4*)(base + k*1024 + t*4);
        s  += v.x + v.y + v.z + v.w;
        ss += v.x*v.x + v.y*v.y + v.z*v.z + v.w*v.w;
    }
    __shared__ float rs[256], rss[256];
    rs[t] = s; rss[t] = ss; __syncthreads();
    for (int off = 128; off; off >>= 1) {
        if (t < off) { rs[t] += rs[t+off]; rss[t] += rss[t+off]; }
        __syncthreads();
    }
    if (t == 0) { red[bx] = rs[0]; red[256 + bx] = rss[0]; }
}

__global__ __launch_bounds__(256) void k_red2(const float* __restrict__ red, float* __restrict__ scal) {
    int t = threadIdx.x;
    __shared__ float rs[256], rss[256];
    rs[t] = red[t]; rss[t] = red[256 + t]; __syncthreads();
    for (int off = 128; off; off >>= 1) {
        if (t < off) { rs[t] += rs[t+off]; rss[t] += rss[t+off]; }
        __syncthreads();
    }
    if (t == 0) {
        float mean = rs[0] * (1.f/1048576.f);
        float var  = rss[0] * (1.f/1048576.f) - mean*mean;
        scal[0] = mean;
        scal[1] = rsqrtf(var + 1e-5f);
    }
}

// ---------- K2: Q = normalize(LN(x)@wqk) [bf16 row-major], Vt = x windows [bf16 ch-major] ----------
__global__ __launch_bounds__(256) void k_qv(const float* __restrict__ x, const float* __restrict__ wqk,
                                            const float* __restrict__ scal,
                                            bf16* __restrict__ Q, bf16* __restrict__ Vt) {
    int t = threadIdx.x, bx = blockIdx.x;
    int y = bx >> 1, x0 = (bx & 1) * 64;
    __shared__ float xs[64][65];
    __shared__ float wl[4096];

    // load 64 pixels x 64 channels; write Vt on the way
    {
        int c = t >> 2, seg = t & 3;
        const float4* xp = (const float4*)(x + (size_t)c*HW + y*128 + x0 + seg*16);
        float f[16];
        #pragma unroll
        for (int k = 0; k < 4; ++k) {
            float4 v = xp[k];
            f[k*4+0] = v.x; f[k*4+1] = v.y; f[k*4+2] = v.z; f[k*4+3] = v.w;
        }
        #pragma unroll
        for (int k = 0; k < 16; ++k) xs[seg*16 + k][c] = f[k];
        int dh = y & 1;
        int base_n = (y >> 1)*64 + ((x0 + seg*16) >> 1);
        bf16* vte = Vt + ((size_t)((dh*2 + 0)*64 + c))*NQ + base_n;
        bf16* vto = Vt + ((size_t)((dh*2 + 1)*64 + c))*NQ + base_n;
        #pragma unroll
        for (int j = 0; j < 8; ++j) { vte[j] = (bf16)f[2*j]; vto[j] = (bf16)f[2*j+1]; }
    }
    // load wqk
    {
        const float4* wp = (const float4*)wqk;
        #pragma unroll
        for (int k = 0; k < 4; ++k) {
            float4 v = wp[t*4 + k];  // wait: need contiguous per-thread
            wl[t*16 + k*4 + 0] = v.x; wl[t*16 + k*4 + 1] = v.y;
            wl[t*16 + k*4 + 2] = v.z; wl[t*16 + k*4 + 3] = v.w;
        }
    }
    __syncthreads();

    float mean = scal[0], rstd = scal[1];
    int p = t >> 2, eg = t & 3;
    float acc[16];
    #pragma unroll
    for (int k = 0; k < 16; ++k) acc[k] = 0.f;
    for (int c = 0; c < 64; ++c) {
        float xv = (xs[p][c] - mean) * rstd;
        const float* wr = &wl[c*64 + eg*16];
        #pragma unroll
        for (int k = 0; k < 16; ++k) acc[k] += xv * wr[k];
    }
    float ss = 0.f;
    #pragma unroll
    for (int k = 0; k < 16; ++k) ss += acc[k]*acc[k];
    ss += __shfl_xor(ss, 1);
    ss += __shfl_xor(ss, 2);
    float inv = 1.f / (sqrtf(ss) + 1e-8f);

    int xp2 = x0 + p;
    int b2 = (y & 1)*2 + (xp2 & 1);
    int nidx = (y >> 1)*64 + (xp2 >> 1);
    bf16* q = Q + ((size_t)b2*NQ + nidx)*64 + eg*16;
    #pragma unroll
    for (int k = 0; k < 16; ++k) q[k] = (bf16)(acc[k]*inv);
}

// ---------- K3: flash attention (no max needed; scores in [0,0.25]) ----------
__global__ __launch_bounds__(256) void k_attn(const bf16* __restrict__ Q, const bf16* __restrict__ Vt,
                                              float* __restrict__ Opart, float* __restrict__ lpart) {
    int bx = blockIdx.x;
    int b2 = bx & 3;            // XCD-friendly: each XCD sees one b2 slice
    int rest = bx >> 2;
    int jh = rest & 1;          // j-split half
    int it = rest >> 1;         // 0..31 -> i-tile of 128 rows
    int tid = threadIdx.x;
    int w = tid >> 6, lane = tid & 63, q = lane >> 4, l15 = lane & 15;
    int ibase = it*128 + w*32;

    const bf16* Qb = Q  + (size_t)b2*NQ*64;
    const bf16* Vb = Vt + (size_t)b2*64*NQ;

    bf16x8 aq[2][2];
    #pragma unroll
    for (int mt = 0; mt < 2; ++mt) {
        const bf16* p = Qb + (size_t)(ibase + mt*16 + l15)*64 + q*8;
        aq[mt][0] = *(const bf16x8*)p;
        aq[mt][1] = *(const bf16x8*)(p + 32);
    }
    f32x4 o[2][4];
    float ls[2][4];
    #pragma unroll
    for (int mt = 0; mt < 2; ++mt)
        #pragma unroll
        for (int n = 0; n < 4; ++n) { o[mt][n] = (f32x4){0.f,0.f,0.f,0.f}; ls[mt][n] = 0.f; }

    __shared__ __align__(16) bf16 plds[4][32][40];

    int j0 = jh * 2048;
    for (int itj = 0; itj < 64; ++itj) {
        int jt = j0 + itj*32;
        bf16x8 bq[2][2];
        #pragma unroll
        for (int nt = 0; nt < 2; ++nt) {
            const bf16* p = Qb + (size_t)(jt + nt*16 + l15)*64 + q*8;
            bq[nt][0] = *(const bf16x8*)p;
            bq[nt][1] = *(const bf16x8*)(p + 32);
        }
        f32x4 z = (f32x4){0.f,0.f,0.f,0.f};
        #pragma unroll
        for (int mt = 0; mt < 2; ++mt) {
            #pragma unroll
            for (int nt = 0; nt < 2; ++nt) {
                f32x4 s = MFMA16(aq[mt][0], bq[nt][0], z);
                s = MFMA16(aq[mt][1], bq[nt][1], s);
                #pragma unroll
                for (int r = 0; r < 4; ++r) {
                    float tt = s[r]*0.125f + 0.125f;
                    float pv = exp_small(tt);
                    ls[mt][r] += pv;
                    plds[w][mt*16 + q*4 + r][nt*16 + l15] = (bf16)pv;
                }
            }
        }
        bf16x8 ap[2];
        #pragma unroll
        for (int mt = 0; mt < 2; ++mt)
            ap[mt] = *(const bf16x8*)&plds[w][mt*16 + l15][q*8];
        #pragma unroll
        for (int nc = 0; nc < 4; ++nc) {
            bf16x8 bv = *(const bf16x8*)(Vb + (size_t)(nc*16 + l15)*NQ + jt + q*8);
            o[0][nc] = MFMA16(ap[0], bv, o[0][nc]);
            o[1][nc] = MFMA16(ap[1], bv, o[1][nc]);
        }
    }

    #pragma unroll
    for (int mt = 0; mt < 2; ++mt)
        #pragma unroll
        for (int r = 0; r < 4; ++r) {
            ls[mt][r] += __shfl_xor(ls[mt][r], 1);
            ls[mt][r] += __shfl_xor(ls[mt][r], 2);
            ls[mt][r] += __shfl_xor(ls[mt][r], 4);
            ls[mt][r] += __shfl_xor(ls[mt][r], 8);
        }

    #pragma unroll
    for (int mt = 0; mt < 2; ++mt) {
        #pragma unroll
        for (int r = 0; r < 4; ++r) {
            int gr = b2*NQ + ibase + mt*16 + q*4 + r;
            float* orow = Opart + ((size_t)jh*16384 + gr)*64;
            #pragma unroll
            for (int nc = 0; nc < 4; ++nc) orow[nc*16 + l15] = o[mt][nc][r];
            if (l15 == 0) lpart[(size_t)jh*16384 + gr] = ls[mt][r];
        }
    }
}

// ---------- K3b: combine j-halves, divide by l, scatter to CHW via the raw-reshape mapping ----------
__global__ __launch_bounds__(256) void k_comb(const float* __restrict__ Op, const float* __restrict__ lp,
                                              float* __restrict__ attn) {
    int tg = blockIdx.x*256 + threadIdx.x;
    int gr = tg >> 2, cq = tg & 3;
    const float4* o0 = (const float4*)(Op + (size_t)gr*64 + cq*16);
    const float4* o1 = (const float4*)(Op + (size_t)16384*64 + (size_t)gr*64 + cq*16);
    float linv = 1.f / (lp[gr] + lp[16384 + gr]);
    int b2 = gr >> 12, nidx = gr & 4095;
    int ch = b2*16 + (nidx >> 8);
    int pbase = (nidx & 255)*64 + cq*16;
    float4* dst = (float4*)(attn + (size_t)ch*HW + pbase);
    #pragma unroll
    for (int k = 0; k < 4; ++k) {
        float4 a = o0[k], b = o1[k];
        float4 r; r.x = (a.x+b.x)*linv; r.y = (a.y+b.y)*linv; r.z = (a.z+b.z)*linv; r.w = (a.w+b.w)*linv;
        dst[k] = r;
    }
}

// ---------- K4: convl (65->64, 1x1) + x  ->  T (HWC bf16) ----------
__global__ __launch_bounds__(256) void k_convl(const float* __restrict__ attn, const float* __restrict__ unet,
                                               const float* __restrict__ x,
                                               const float* __restrict__ wl, const float* __restrict__ bl,
                                               bf16* __restrict__ T) {
    int t = threadIdx.x, bx = blockIdx.x;
    int p0 = bx * 64;
    __shared__ float als[64][65];
    __shared__ float xls[64][65];
    __shared__ float wls[65*64];
    {
        int ci = t >> 2, seg = t & 3;
        const float4* ap = (const float4*)(attn + (size_t)ci*HW + p0 + seg*16);
        const float4* xp = (const float4*)(x    + (size_t)ci*HW + p0 + seg*16);
        #pragma unroll
        for (int k = 0; k < 4; ++k) {
            float4 v = ap[k];
            als[seg*16 + k*4 + 0][ci] = v.x; als[seg*16 + k*4 + 1][ci] = v.y;
            als[seg*16 + k*4 + 2][ci] = v.z; als[seg*16 + k*4 + 3][ci] = v.w;
            float4 u = xp[k];
            xls[seg*16 + k*4 + 0][ci] = u.x; xls[seg*16 + k*4 + 1][ci] = u.y;
            xls[seg*16 + k*4 + 2][ci] = u.z; xls[seg*16 + k*4 + 3][ci] = u.w;
        }
        for (int i = t; i < 65*64; i += 256) wls[i] = wl[i];
    }
    __syncthreads();

    int pg = t & 15, cg = t >> 4;   // 4 pixels, 4 out-channels each
    float acc[4][4];
    #pragma unroll
    for (int i = 0; i < 4; ++i)
        #pragma unroll
        for (int k = 0; k < 4; ++k) acc[i][k] = 0.f;

    for (int ci = 0; ci < 64; ++ci) {
        float wv[4];
        #pragma unroll
        for (int k = 0; k < 4; ++k) wv[k] = wls[(cg*4 + k)*65 + ci];
        #pragma unroll
        for (int i = 0; i < 4; ++i) {
            float v = als[pg*4 + i][ci];
            #pragma unroll
            for (int k = 0; k < 4; ++k) acc[i][k] += v * wv[k];
        }
    }
    {   // unet channel (ci = 64)
        float wv[4];
        #pragma unroll
        for (int k = 0; k < 4; ++k) wv[k] = wls[(cg*4 + k)*65 + 64];
        #pragma unroll
        for (int i = 0; i < 4; ++i) {
            float u = unet[p0 + pg*4 + i];
            #pragma unroll
            for (int k = 0; k < 4; ++k) acc[i][k] += u * wv[k];
        }
    }
    #pragma unroll
    for (int i = 0; i < 4; ++i) {
        #pragma unroll
        for (int k = 0; k < 4; ++k) {
            float v = xls[pg*4 + i][cg*4 + k] + acc[i][k] + bl[cg*4 + k];
            T[(size_t)(p0 + pg*4 + i)*64 + cg*4 + k] = (bf16)v;
        }
    }
}

// ---------- K5/K6: 3x3 conv (dilation d) + bias + relu, HWC bf16 -> HWC bf16 ----------
__global__ __launch_bounds__(256) void k_conv3x3(const bf16* __restrict__ IN, const bf16* __restrict__ WT,
                                                 const float* __restrict__ B, bf16* __restrict__ OUT,
                                                 int dil) {
    int tid = threadIdx.x, bx = blockIdx.x;
    int y = bx >> 1, x0 = (bx & 1)*64;
    int w = tid >> 6, lane = tid & 63, q = lane >> 4, l15 = lane & 15;
    int xb = x0 + w*16;
    f32x4 o[4];
    #pragma unroll
    for (int cb = 0; cb < 4; ++cb) o[cb] = (f32x4){0.f,0.f,0.f,0.f};

    #pragma unroll
    for (int ky = 0; ky < 3; ++ky) {
        int yy = y + (ky - 1)*dil;
        bool yok = (yy >= 0) && (yy < 128);
        #pragma unroll
        for (int kx = 0; kx < 3; ++kx) {
            int xx = xb + l15 + (kx - 1)*dil;
            bool ok = yok && (xx >= 0) && (xx < 128);
            bf16x8 alo = {}, ahi = {};
            if (ok) {
                const bf16* ip = IN + (size_t)(yy*128 + xx)*64 + q*8;
                alo = *(const bf16x8*)ip;
                ahi = *(const bf16x8*)(ip + 32);
            }
            int tap = ky*3 + kx;
            #pragma unroll
            for (int cb = 0; cb < 4; ++cb) {
                const bf16* wp = WT + (size_t)(tap*64 + cb*16 + l15)*64 + q*8;
                bf16x8 blo = *(const bf16x8*)wp;
                bf16x8 bhi = *(const bf16x8*)(wp + 32);
                o[cb] = MFMA16(alo, blo, o[cb]);
                o[cb] = MFMA16(ahi, bhi, o[cb]);
            }
        }
    }
    #pragma unroll
    for (int cb = 0; cb < 4; ++cb) {
        int co = cb*16 + l15;
        float bias = B[co];
        #pragma unroll
        for (int r = 0; r < 4; ++r) {
            float v = o[cb][r] + bias;
            v = fmaxf(v, 0.f);
            OUT[(size_t)(y*128 + x0 + w*16 + q*4 + r)*64 + co] = (bf16)v;
        }
    }
}

// ---------- K7: conv3 1x1 + bias + x -> d_out (CHW fp32) ----------
__global__ __launch_bounds__(256) void k_conv3(const bf16* __restrict__ T3, const bf16* __restrict__ W3,
                                               const float* __restrict__ b3, const float* __restrict__ x,
                                               float* __restrict__ out) {
    int tid = threadIdx.x, bx = blockIdx.x;
    int w = tid >> 6, lane = tid & 63, q = lane >> 4, l15 = lane & 15;
    int p0 = bx*64 + w*16;
    const bf16* bp = T3 + (size_t)(p0 + l15)*64 + q*8;
    bf16x8 blo = *(const bf16x8*)bp;
    bf16x8 bhi = *(const bf16x8*)(bp + 32);
    f32x4 z = (f32x4){0.f,0.f,0.f,0.f};
    f32x4 o[4];
    #pragma unroll
    for (int mt = 0; mt < 4; ++mt) {
        const bf16* ap = W3 + (size_t)(mt*16 + l15)*64 + q*8;
        bf16x8 alo = *(const bf16x8*)ap;
        bf16x8 ahi = *(const bf16x8*)(ap + 32);
        f32x4 s = MFMA16(alo, blo, z);
        o[mt] = MFMA16(ahi, bhi, s);
    }
    #pragma unroll
    for (int mt = 0; mt < 4; ++mt) {
        #pragma unroll
        for (int r = 0; r < 4; ++r) {
            int co = mt*16 + q*4 + r;
            size_t idx = (size_t)co*HW + p0 + l15;
            out[idx] = x[idx] + b3[co] + o[mt][r];
        }
    }
}

extern "C" void kernel_launch(void* const* d_in, const int* in_sizes, int n_in,
                              void* d_out, int out_size, void* d_ws, size_t ws_size,
                              hipStream_t stream) {
    (void)in_sizes; (void)n_in; (void)out_size; (void)ws_size;
    const float* x    = (const float*)d_in[0];
    const float* unet = (const float*)d_in[1];
    const float* wqk  = (const float*)d_in[2];
    const float* c1w  = (const float*)d_in[3];
    const float* c1b  = (const float*)d_in[4];
    const float* c2w  = (const float*)d_in[5];
    const float* c2b  = (const float*)d_in[6];
    const float* c3w  = (const float*)d_in[7];
    const float* c3b  = (const float*)d_in[8];
    const float* clw  = (const float*)d_in[9];
    const float* clb  = (const float*)d_in[10];
    float* out = (float*)d_out;

    char* ws = (char*)d_ws;
    float* red   = (float*)(ws + OFF_RED);
    float* scal  = (float*)(ws + OFF_SCAL);
    bf16*  Q     = (bf16*)(ws + OFF_Q);
    bf16*  Vt    = (bf16*)(ws + OFF_VT);
    float* Opart = (float*)(ws + OFF_OP);
    float* lpart = (float*)(ws + OFF_LP);
    float* attn  = (float*)(ws + OFF_AT);
    bf16*  T     = (bf16*)(ws + OFF_T);
    bf16*  T2    = (bf16*)(ws + OFF_T2);
    bf16*  T3    = (bf16*)(ws + OFF_T3);
    bf16*  W1    = (bf16*)(ws + OFF_W1);
    bf16*  W2    = (bf16*)(ws + OFF_W2);
    bf16*  W3    = (bf16*)(ws + OFF_W3);

    k_prep_w<<<dim3(304), dim3(256), 0, stream>>>(c1w, c2w, c3w, W1, W2, W3);
    k_red1<<<dim3(256), dim3(256), 0, stream>>>(x, red);
    k_red2<<<dim3(1),   dim3(256), 0, stream>>>(red, scal);
    k_qv<<<dim3(256),   dim3(256), 0, stream>>>(x, wqk, scal, Q, Vt);
    k_attn<<<dim3(256), dim3(256), 0, stream>>>(Q, Vt, Opart, lpart);
    k_comb<<<dim3(256), dim3(256), 0, stream>>>(Opart, lpart, attn);
    k_convl<<<dim3(256),dim3(256), 0, stream>>>(attn, unet, x, clw, clb, T);
    k_conv3x3<<<dim3(256), dim3(256), 0, stream>>>(T,  W1, c1b, T2, 1);
    k_conv3x3<<<dim3(256), dim3(256), 0, stream>>>(T2, W2, c2b, T3, 2);
    k_conv3<<<dim3(256), dim3(256), 0, stream>>>(T3, W3, c3b, x, out);
}

// Round 2
// 170.041 us; speedup vs baseline: 1.1319x; 1.1319x over previous
//
#include <hip/hip_runtime.h>

typedef __bf16 bf16;
typedef bf16 bf16x8 __attribute__((ext_vector_type(8)));
typedef float f32x4 __attribute__((ext_vector_type(4)));

#define MFMA16(a,b,c) __builtin_amdgcn_mfma_f32_16x16x32_bf16(a,b,c,0,0,0)

#define HW 16384   // 128*128
#define NQ 4096    // positions per window

// ---- workspace layout (bytes) ----
constexpr size_t OFF_RED  = 0;                                 // 2 KB partial sums
constexpr size_t OFF_Q    = 4096;                              // bf16 (4,4096,64)  2 MB
constexpr size_t OFF_VT   = OFF_Q  + (size_t)2097152;          // bf16 (4,64,4096)  2 MB
constexpr size_t OFF_OP   = OFF_VT + (size_t)2097152;          // fp32 (4,16384,64) 16 MB
constexpr size_t OFF_LP   = OFF_OP + (size_t)4*16384*64*4;     // fp32 (4,16384)  256 KB
constexpr size_t OFF_T    = OFF_LP + (size_t)262144;           // bf16 HWC 2 MB
constexpr size_t OFF_T2   = OFF_OP;                            // alias OP (dead after k_convl)
constexpr size_t OFF_T3   = OFF_OP + (size_t)2097152;
constexpr size_t OFF_W1   = OFF_T  + (size_t)2097152;          // bf16 (9,64,64)
constexpr size_t OFF_W2   = OFF_W1 + 73728;
constexpr size_t OFF_W3   = OFF_W2 + 73728;                    // bf16 (64,64)

__device__ inline float exp_small(float t) {
    // e^t for t in [-0.01, 0.26]; deg-5 Taylor, max rel err ~4e-7
    return 1.f + t*(1.f + t*(0.5f + t*(0.16666667f + t*(0.041666668f + t*0.0083333338f))));
}

// ---------- K0: fused LN partial reduction (bx<256) + weight prep (bx>=256) ----------
__global__ __launch_bounds__(256) void k_red1w(const float* __restrict__ x, float* __restrict__ red,
                                               const float* __restrict__ w1, const float* __restrict__ w2,
                                               const float* __restrict__ w3,
                                               bf16* __restrict__ W1, bf16* __restrict__ W2, bf16* __restrict__ W3) {
    int t = threadIdx.x, bx = blockIdx.x;
    if (bx >= 256) {
        int g = (bx - 256) * 256 + t;
        if (g < 36864) {
            int tap = g >> 12, co = (g >> 6) & 63, ci = g & 63;
            W1[g] = (bf16)w1[(co*64 + ci)*9 + tap];
        } else if (g < 73728) {
            int d = g - 36864;
            int tap = d >> 12, co = (d >> 6) & 63, ci = d & 63;
            W2[d] = (bf16)w2[(co*64 + ci)*9 + tap];
        } else if (g < 77824) {
            int d = g - 73728;
            W3[d] = (bf16)w3[d];
        }
        return;
    }
    float s = 0.f, ss = 0.f;
    const float* base = x + (size_t)bx*4096;
    #pragma unroll
    for (int k = 0; k < 4; ++k) {
        float4 v = *(const float4*)(base + k*1024 + t*4);
        s  += v.x + v.y + v.z + v.w;
        ss += v.x*v.x + v.y*v.y + v.z*v.z + v.w*v.w;
    }
    __shared__ float rs[256], rss[256];
    rs[t] = s; rss[t] = ss; __syncthreads();
    for (int off = 128; off; off >>= 1) {
        if (t < off) { rs[t] += rs[t+off]; rss[t] += rss[t+off]; }
        __syncthreads();
    }
    if (t == 0) { red[bx] = rs[0]; red[256 + bx] = rss[0]; }
}

// ---------- K2: Q = normalize(LN(x)@wqk) [bf16 row-major], Vt = x windows [bf16 ch-major] ----------
// (final LN stats computed per-block from the 512 partials — cheaper than a separate 1-block kernel)
__global__ __launch_bounds__(256) void k_qv(const float* __restrict__ x, const float* __restrict__ wqk,
                                            const float* __restrict__ red,
                                            bf16* __restrict__ Q, bf16* __restrict__ Vt) {
    int t = threadIdx.x, bx = blockIdx.x;
    int y = bx >> 1, x0 = (bx & 1) * 64;
    __shared__ float xs[64][65];
    __shared__ float wl[4096];
    __shared__ float rs[256], rss[256], sc[2];

    rs[t] = red[t]; rss[t] = red[256 + t];
    __syncthreads();
    for (int off = 128; off; off >>= 1) {
        if (t < off) { rs[t] += rs[t+off]; rss[t] += rss[t+off]; }
        __syncthreads();
    }
    if (t == 0) {
        float mean = rs[0] * (1.f/1048576.f);
        float var  = rss[0] * (1.f/1048576.f) - mean*mean;
        sc[0] = mean;
        sc[1] = rsqrtf(var + 1e-5f);
    }

    // load 64 pixels x 64 channels; write Vt on the way
    {
        int c = t >> 2, seg = t & 3;
        const float4* xp = (const float4*)(x + (size_t)c*HW + y*128 + x0 + seg*16);
        float f[16];
        #pragma unroll
        for (int k = 0; k < 4; ++k) {
            float4 v = xp[k];
            f[k*4+0] = v.x; f[k*4+1] = v.y; f[k*4+2] = v.z; f[k*4+3] = v.w;
        }
        #pragma unroll
        for (int k = 0; k < 16; ++k) xs[seg*16 + k][c] = f[k];
        int dh = y & 1;
        int base_n = (y >> 1)*64 + ((x0 + seg*16) >> 1);
        bf16* vte = Vt + ((size_t)((dh*2 + 0)*64 + c))*NQ + base_n;
        bf16* vto = Vt + ((size_t)((dh*2 + 1)*64 + c))*NQ + base_n;
        #pragma unroll
        for (int j = 0; j < 8; ++j) { vte[j] = (bf16)f[2*j]; vto[j] = (bf16)f[2*j+1]; }
    }
    // load wqk
    {
        const float4* wp = (const float4*)wqk;
        #pragma unroll
        for (int k = 0; k < 4; ++k) {
            float4 v = wp[t*4 + k];
            wl[t*16 + k*4 + 0] = v.x; wl[t*16 + k*4 + 1] = v.y;
            wl[t*16 + k*4 + 2] = v.z; wl[t*16 + k*4 + 3] = v.w;
        }
    }
    __syncthreads();

    float mean = sc[0], rstd = sc[1];
    int p = t >> 2, eg = t & 3;
    float acc[16];
    #pragma unroll
    for (int k = 0; k < 16; ++k) acc[k] = 0.f;
    for (int c = 0; c < 64; ++c) {
        float xv = (xs[p][c] - mean) * rstd;
        const float* wr = &wl[c*64 + eg*16];
        #pragma unroll
        for (int k = 0; k < 16; ++k) acc[k] += xv * wr[k];
    }
    float ss = 0.f;
    #pragma unroll
    for (int k = 0; k < 16; ++k) ss += acc[k]*acc[k];
    ss += __shfl_xor(ss, 1);
    ss += __shfl_xor(ss, 2);
    float inv = 1.f / (sqrtf(ss) + 1e-8f);

    int xp2 = x0 + p;
    int b2 = (y & 1)*2 + (xp2 & 1);
    int nidx = (y >> 1)*64 + (xp2 >> 1);
    bf16* q = Q + ((size_t)b2*NQ + nidx)*64 + eg*16;
    #pragma unroll
    for (int k = 0; k < 16; ++k) q[k] = (bf16)(acc[k]*inv);
}

// ---------- K3: flash attention, j split 4-way, LDS-staged B-side tiles ----------
__global__ __launch_bounds__(256) void k_attn(const bf16* __restrict__ Q, const bf16* __restrict__ Vt,
                                              float* __restrict__ Opart, float* __restrict__ lpart) {
    int bx = blockIdx.x;
    int b2 = bx & 3;            // XCD-friendly
    int rest = bx >> 2;
    int jq = rest & 3;          // j quarter (1024 cols)
    int it = rest >> 2;         // 0..31 -> i-tile of 128 rows
    int tid = threadIdx.x;
    int w = tid >> 6, lane = tid & 63, q = lane >> 4, l15 = lane & 15;
    int ibase = it*128 + w*32;

    const bf16* Qb = Q  + (size_t)b2*NQ*64;
    const bf16* Vb = Vt + (size_t)b2*64*NQ;

    bf16x8 aq[2][2];
    #pragma unroll
    for (int mt = 0; mt < 2; ++mt) {
        const bf16* p = Qb + (size_t)(ibase + mt*16 + l15)*64 + q*8;
        aq[mt][0] = *(const bf16x8*)p;
        aq[mt][1] = *(const bf16x8*)(p + 32);
    }
    f32x4 o[2][4];
    float ls[2][4];
    #pragma unroll
    for (int mt = 0; mt < 2; ++mt)
        #pragma unroll
        for (int n = 0; n < 4; ++n) { o[mt][n] = (f32x4){0.f,0.f,0.f,0.f}; ls[mt][n] = 0.f; }

    __shared__ __align__(16) bf16 Qs[32][68];   // j-rows of Q (B for QK), pad->~4-way max
    __shared__ __align__(16) bf16 Vs[64][40];   // ch-major V tile (B for PV), pad->2-way
    __shared__ __align__(16) bf16 plds[4][32][40];

    int qrow = tid >> 3, qc8 = tid & 7;
    int vch = tid >> 2, vsg = tid & 3;
    int j0 = jq * 1024;
    for (int itj = 0; itj < 32; ++itj) {
        int jt = j0 + itj*32;
        __syncthreads();
        *(bf16x8*)&Qs[qrow][qc8*8] = *(const bf16x8*)(Qb + (size_t)(jt + qrow)*64 + qc8*8);
        *(bf16x8*)&Vs[vch][vsg*8]  = *(const bf16x8*)(Vb + (size_t)vch*NQ + jt + vsg*8);
        __syncthreads();

        f32x4 z = (f32x4){0.f,0.f,0.f,0.f};
        #pragma unroll
        for (int nt = 0; nt < 2; ++nt) {
            bf16x8 b0 = *(const bf16x8*)&Qs[nt*16 + l15][q*8];
            bf16x8 b1 = *(const bf16x8*)&Qs[nt*16 + l15][32 + q*8];
            #pragma unroll
            for (int mt = 0; mt < 2; ++mt) {
                f32x4 s = MFMA16(aq[mt][0], b0, z);
                s = MFMA16(aq[mt][1], b1, s);
                #pragma unroll
                for (int r = 0; r < 4; ++r) {
                    float tt = s[r]*0.125f + 0.125f;
                    float pv = exp_small(tt);
                    ls[mt][r] += pv;
                    plds[w][mt*16 + q*4 + r][nt*16 + l15] = (bf16)pv;
                }
            }
        }
        bf16x8 ap0 = *(const bf16x8*)&plds[w][l15][q*8];
        bf16x8 ap1 = *(const bf16x8*)&plds[w][16 + l15][q*8];
        #pragma unroll
        for (int nc = 0; nc < 4; ++nc) {
            bf16x8 bv = *(const bf16x8*)&Vs[nc*16 + l15][q*8];
            o[0][nc] = MFMA16(ap0, bv, o[0][nc]);
            o[1][nc] = MFMA16(ap1, bv, o[1][nc]);
        }
    }

    #pragma unroll
    for (int mt = 0; mt < 2; ++mt)
        #pragma unroll
        for (int r = 0; r < 4; ++r) {
            ls[mt][r] += __shfl_xor(ls[mt][r], 1);
            ls[mt][r] += __shfl_xor(ls[mt][r], 2);
            ls[mt][r] += __shfl_xor(ls[mt][r], 4);
            ls[mt][r] += __shfl_xor(ls[mt][r], 8);
        }

    #pragma unroll
    for (int mt = 0; mt < 2; ++mt) {
        #pragma unroll
        for (int r = 0; r < 4; ++r) {
            int gr = b2*NQ + ibase + mt*16 + q*4 + r;
            float* orow = Opart + ((size_t)jq*16384 + gr)*64;
            #pragma unroll
            for (int nc = 0; nc < 4; ++nc) orow[nc*16 + l15] = o[mt][nc][r];
            if (l15 == 0) lpart[(size_t)jq*16384 + gr] = ls[mt][r];
        }
    }
}

// ---------- K4: combine partials + convl (65->64, 1x1) + x  ->  T (HWC bf16) ----------
__global__ __launch_bounds__(256) void k_convl(const float* __restrict__ Op, const float* __restrict__ lp,
                                               const float* __restrict__ unet, const float* __restrict__ x,
                                               const float* __restrict__ wl, const float* __restrict__ bl,
                                               bf16* __restrict__ T) {
    int t = threadIdx.x, bx = blockIdx.x;
    int p0 = bx * 64;
    __shared__ float als[64][65];
    __shared__ float xls[64][65];
    __shared__ float wls[65*64];
    {
        int ci = t >> 2, seg = t & 3;
        // attn[ci][p0+pc] = (sum_parts Op[part][gr][pc]) / l  with gr = (ci>>4)*4096 + (ci&15)*256 + bx
        int gr = ((ci >> 4) * 4096) + ((ci & 15) * 256) + bx;
        float linv = 1.f / (lp[gr] + lp[16384 + gr] + lp[32768 + gr] + lp[49152 + gr]);
        const float4* q0 = (const float4*)(Op + (size_t)gr*64 + seg*16);
        const float4* xp = (const float4*)(x + (size_t)ci*HW + p0 + seg*16);
        #pragma unroll
        for (int k = 0; k < 4; ++k) {
            float4 a = q0[k], b = q0[k + 262144], c = q0[k + 524288], d = q0[k + 786432];
            als[seg*16 + k*4 + 0][ci] = (a.x + b.x + c.x + d.x) * linv;
            als[seg*16 + k*4 + 1][ci] = (a.y + b.y + c.y + d.y) * linv;
            als[seg*16 + k*4 + 2][ci] = (a.z + b.z + c.z + d.z) * linv;
            als[seg*16 + k*4 + 3][ci] = (a.w + b.w + c.w + d.w) * linv;
            float4 u = xp[k];
            xls[seg*16 + k*4 + 0][ci] = u.x; xls[seg*16 + k*4 + 1][ci] = u.y;
            xls[seg*16 + k*4 + 2][ci] = u.z; xls[seg*16 + k*4 + 3][ci] = u.w;
        }
        for (int i = t; i < 65*64; i += 256) wls[i] = wl[i];
    }
    __syncthreads();

    int pg = t & 15, cg = t >> 4;   // 4 pixels, 4 out-channels each
    float acc[4][4];
    #pragma unroll
    for (int i = 0; i < 4; ++i)
        #pragma unroll
        for (int k = 0; k < 4; ++k) acc[i][k] = 0.f;

    for (int ci = 0; ci < 64; ++ci) {
        float wv[4];
        #pragma unroll
        for (int k = 0; k < 4; ++k) wv[k] = wls[(cg*4 + k)*65 + ci];
        #pragma unroll
        for (int i = 0; i < 4; ++i) {
            float v = als[pg*4 + i][ci];
            #pragma unroll
            for (int k = 0; k < 4; ++k) acc[i][k] += v * wv[k];
        }
    }
    {   // unet channel (ci = 64)
        float wv[4];
        #pragma unroll
        for (int k = 0; k < 4; ++k) wv[k] = wls[(cg*4 + k)*65 + 64];
        #pragma unroll
        for (int i = 0; i < 4; ++i) {
            float u = unet[p0 + pg*4 + i];
            #pragma unroll
            for (int k = 0; k < 4; ++k) acc[i][k] += u * wv[k];
        }
    }
    #pragma unroll
    for (int i = 0; i < 4; ++i) {
        #pragma unroll
        for (int k = 0; k < 4; ++k) {
            float v = xls[pg*4 + i][cg*4 + k] + acc[i][k] + bl[cg*4 + k];
            T[(size_t)(p0 + pg*4 + i)*64 + cg*4 + k] = (bf16)v;
        }
    }
}

// ---------- K5/K6: 3x3 conv (dilation d) + bias + relu, HWC bf16 -> HWC bf16, co-split ----------
__global__ __launch_bounds__(256) void k_conv3x3(const bf16* __restrict__ IN, const bf16* __restrict__ WT,
                                                 const float* __restrict__ B, bf16* __restrict__ OUT,
                                                 int dil) {
    int tid = threadIdx.x, bx = blockIdx.x;
    int y = bx >> 2, xh = (bx >> 1) & 1, coh = bx & 1;
    int w = tid >> 6, lane = tid & 63, q = lane >> 4, l15 = lane & 15;
    int xb = xh*64 + w*16;
    f32x4 o[2];
    o[0] = (f32x4){0.f,0.f,0.f,0.f};
    o[1] = (f32x4){0.f,0.f,0.f,0.f};

    #pragma unroll
    for (int ky = 0; ky < 3; ++ky) {
        int yy = y + (ky - 1)*dil;
        bool yok = (yy >= 0) && (yy < 128);
        #pragma unroll
        for (int kx = 0; kx < 3; ++kx) {
            int xx = xb + l15 + (kx - 1)*dil;
            bool ok = yok && (xx >= 0) && (xx < 128);
            bf16x8 alo = {}, ahi = {};
            if (ok) {
                const bf16* ip = IN + (size_t)(yy*128 + xx)*64 + q*8;
                alo = *(const bf16x8*)ip;
                ahi = *(const bf16x8*)(ip + 32);
            }
            int tap = ky*3 + kx;
            #pragma unroll
            for (int cb = 0; cb < 2; ++cb) {
                const bf16* wp = WT + (size_t)(tap*64 + coh*32 + cb*16 + l15)*64 + q*8;
                bf16x8 blo = *(const bf16x8*)wp;
                bf16x8 bhi = *(const bf16x8*)(wp + 32);
                o[cb] = MFMA16(alo, blo, o[cb]);
                o[cb] = MFMA16(ahi, bhi, o[cb]);
            }
        }
    }
    #pragma unroll
    for (int cb = 0; cb < 2; ++cb) {
        int co = coh*32 + cb*16 + l15;
        float bias = B[co];
        #pragma unroll
        for (int r = 0; r < 4; ++r) {
            float v = o[cb][r] + bias;
            v = fmaxf(v, 0.f);
            OUT[(size_t)(y*128 + xb + q*4 + r)*64 + co] = (bf16)v;
        }
    }
}

// ---------- K7: conv3 1x1 + bias + x -> d_out (CHW fp32) ----------
__global__ __launch_bounds__(256) void k_conv3(const bf16* __restrict__ T3, const bf16* __restrict__ W3,
                                               const float* __restrict__ b3, const float* __restrict__ x,
                                               float* __restrict__ out) {
    int tid = threadIdx.x, bx = blockIdx.x;
    int w = tid >> 6, lane = tid & 63, q = lane >> 4, l15 = lane & 15;
    int p0 = bx*64 + w*16;
    const bf16* bp = T3 + (size_t)(p0 + l15)*64 + q*8;
    bf16x8 blo = *(const bf16x8*)bp;
    bf16x8 bhi = *(const bf16x8*)(bp + 32);
    f32x4 z = (f32x4){0.f,0.f,0.f,0.f};
    f32x4 o[4];
    #pragma unroll
    for (int mt = 0; mt < 4; ++mt) {
        const bf16* ap = W3 + (size_t)(mt*16 + l15)*64 + q*8;
        bf16x8 alo = *(const bf16x8*)ap;
        bf16x8 ahi = *(const bf16x8*)(ap + 32);
        f32x4 s = MFMA16(alo, blo, z);
        o[mt] = MFMA16(ahi, bhi, s);
    }
    #pragma unroll
    for (int mt = 0; mt < 4; ++mt) {
        #pragma unroll
        for (int r = 0; r < 4; ++r) {
            int co = mt*16 + q*4 + r;
            size_t idx = (size_t)co*HW + p0 + l15;
            out[idx] = x[idx] + b3[co] + o[mt][r];
        }
    }
}

extern "C" void kernel_launch(void* const* d_in, const int* in_sizes, int n_in,
                              void* d_out, int out_size, void* d_ws, size_t ws_size,
                              hipStream_t stream) {
    (void)in_sizes; (void)n_in; (void)out_size; (void)ws_size;
    const float* x    = (const float*)d_in[0];
    const float* unet = (const float*)d_in[1];
    const float* wqk  = (const float*)d_in[2];
    const float* c1w  = (const float*)d_in[3];
    const float* c1b  = (const float*)d_in[4];
    const float* c2w  = (const float*)d_in[5];
    const float* c2b  = (const float*)d_in[6];
    const float* c3w  = (const float*)d_in[7];
    const float* c3b  = (const float*)d_in[8];
    const float* clw  = (const float*)d_in[9];
    const float* clb  = (const float*)d_in[10];
    float* out = (float*)d_out;

    char* ws = (char*)d_ws;
    float* red   = (float*)(ws + OFF_RED);
    bf16*  Q     = (bf16*)(ws + OFF_Q);
    bf16*  Vt    = (bf16*)(ws + OFF_VT);
    float* Opart = (float*)(ws + OFF_OP);
    float* lpart = (float*)(ws + OFF_LP);
    bf16*  T     = (bf16*)(ws + OFF_T);
    bf16*  T2    = (bf16*)(ws + OFF_T2);
    bf16*  T3    = (bf16*)(ws + OFF_T3);
    bf16*  W1    = (bf16*)(ws + OFF_W1);
    bf16*  W2    = (bf16*)(ws + OFF_W2);
    bf16*  W3    = (bf16*)(ws + OFF_W3);

    k_red1w<<<dim3(560), dim3(256), 0, stream>>>(x, red, c1w, c2w, c3w, W1, W2, W3);
    k_qv<<<dim3(256),    dim3(256), 0, stream>>>(x, wqk, red, Q, Vt);
    k_attn<<<dim3(512),  dim3(256), 0, stream>>>(Q, Vt, Opart, lpart);
    k_convl<<<dim3(256), dim3(256), 0, stream>>>(Opart, lpart, unet, x, clw, clb, T);
    k_conv3x3<<<dim3(512), dim3(256), 0, stream>>>(T,  W1, c1b, T2, 1);
    k_conv3x3<<<dim3(512), dim3(256), 0, stream>>>(T2, W2, c2b, T3, 2);
    k_conv3<<<dim3(256), dim3(256), 0, stream>>>(T3, W3, c3b, x, out);
}

// Round 3
// 163.374 us; speedup vs baseline: 1.1781x; 1.0408x over previous
//
#include <hip/hip_runtime.h>

typedef __bf16 bf16;
typedef bf16 bf16x8 __attribute__((ext_vector_type(8)));
typedef bf16 bf16x4 __attribute__((ext_vector_type(4)));
typedef float f32x4 __attribute__((ext_vector_type(4)));

#define MFMA16(a,b,c) __builtin_amdgcn_mfma_f32_16x16x32_bf16(a,b,c,0,0,0)

#define HW 16384   // 128*128
#define NQ 4096    // positions per window

// ---- workspace layout (bytes) ----
constexpr size_t OFF_RED  = 0;                                 // 2 KB partial sums
constexpr size_t OFF_Q    = 4096;                              // bf16 (4,4096,64)  2 MB
constexpr size_t OFF_VT   = OFF_Q  + (size_t)2097152;          // bf16 (4,64,4096)  2 MB
constexpr size_t OFF_OP   = OFF_VT + (size_t)2097152;          // bf16 (8,16384,64) 16 MB
constexpr size_t OFF_LP   = OFF_OP + (size_t)16777216;         // fp32 (8,16384)  512 KB
constexpr size_t OFF_T    = OFF_LP + (size_t)524288;           // bf16 HWC 2 MB
constexpr size_t OFF_T2   = OFF_OP;                            // alias OP (dead after k_convl)
constexpr size_t OFF_T3   = OFF_OP + (size_t)2097152;
constexpr size_t OFF_W1   = OFF_T  + (size_t)2097152;          // bf16 (9,64,64)
constexpr size_t OFF_W2   = OFF_W1 + 73728;
constexpr size_t OFF_W3   = OFF_W2 + 73728;                    // bf16 (64,64)

// exp((s+1)/8) for s in [-1,1]: deg-3, coeffs e^{1/8}/(8^k k!), max err ~1.2e-5
#define EC0 1.13314845f
#define EC1 0.141643556f
#define EC2 0.0088527222f
#define EC3 3.6886342e-4f

// ---------- K0: fused LN partial reduction (bx<256) + weight prep (bx>=256) ----------
__global__ __launch_bounds__(256) void k_red1w(const float* __restrict__ x, float* __restrict__ red,
                                               const float* __restrict__ w1, const float* __restrict__ w2,
                                               const float* __restrict__ w3,
                                               bf16* __restrict__ W1, bf16* __restrict__ W2, bf16* __restrict__ W3) {
    int t = threadIdx.x, bx = blockIdx.x;
    if (bx >= 256) {
        int g = (bx - 256) * 256 + t;
        if (g < 36864) {
            int tap = g >> 12, co = (g >> 6) & 63, ci = g & 63;
            W1[g] = (bf16)w1[(co*64 + ci)*9 + tap];
        } else if (g < 73728) {
            int d = g - 36864;
            int tap = d >> 12, co = (d >> 6) & 63, ci = d & 63;
            W2[d] = (bf16)w2[(co*64 + ci)*9 + tap];
        } else if (g < 77824) {
            int d = g - 73728;
            W3[d] = (bf16)w3[d];
        }
        return;
    }
    float s = 0.f, ss = 0.f;
    const float* base = x + (size_t)bx*4096;
    #pragma unroll
    for (int k = 0; k < 4; ++k) {
        float4 v = *(const float4*)(base + k*1024 + t*4);
        s  += v.x + v.y + v.z + v.w;
        ss += v.x*v.x + v.y*v.y + v.z*v.z + v.w*v.w;
    }
    __shared__ float rs[256], rss[256];
    rs[t] = s; rss[t] = ss; __syncthreads();
    for (int off = 128; off; off >>= 1) {
        if (t < off) { rs[t] += rs[t+off]; rss[t] += rss[t+off]; }
        __syncthreads();
    }
    if (t == 0) { red[bx] = rs[0]; red[256 + bx] = rss[0]; }
}

// ---------- K2: Q = normalize(LN(x)@wqk) [bf16 row-major], Vt = x windows [bf16 ch-major] ----------
__global__ __launch_bounds__(256) void k_qv(const float* __restrict__ x, const float* __restrict__ wqk,
                                            const float* __restrict__ red,
                                            bf16* __restrict__ Q, bf16* __restrict__ Vt) {
    int t = threadIdx.x, bx = blockIdx.x;
    int y = bx >> 2, x0 = (bx & 3) * 32;
    __shared__ float xs[32][65];
    __shared__ float wl[4096];
    __shared__ float rs[256], rss[256], sc[2];

    rs[t] = red[t]; rss[t] = red[256 + t];
    __syncthreads();
    for (int off = 128; off; off >>= 1) {
        if (t < off) { rs[t] += rs[t+off]; rss[t] += rss[t+off]; }
        __syncthreads();
    }
    if (t == 0) {
        float mean = rs[0] * (1.f/1048576.f);
        float var  = rss[0] * (1.f/1048576.f) - mean*mean;
        sc[0] = mean;
        sc[1] = rsqrtf(var + 1e-5f);
    }

    // load 32 pixels x 64 channels; write Vt on the way
    {
        int c = t >> 2, seg = t & 3;
        const float4* xp = (const float4*)(x + (size_t)c*HW + y*128 + x0 + seg*8);
        float f[8];
        float4 v0 = xp[0], v1 = xp[1];
        f[0]=v0.x; f[1]=v0.y; f[2]=v0.z; f[3]=v0.w;
        f[4]=v1.x; f[5]=v1.y; f[6]=v1.z; f[7]=v1.w;
        #pragma unroll
        for (int k = 0; k < 8; ++k) xs[seg*8 + k][c] = f[k];
        int dh = y & 1;
        int base_n = (y >> 1)*64 + ((x0 + seg*8) >> 1);
        bf16* vte = Vt + ((size_t)((dh*2 + 0)*64 + c))*NQ + base_n;
        bf16* vto = Vt + ((size_t)((dh*2 + 1)*64 + c))*NQ + base_n;
        #pragma unroll
        for (int j = 0; j < 4; ++j) { vte[j] = (bf16)f[2*j]; vto[j] = (bf16)f[2*j+1]; }
    }
    // load wqk (64x64 fp32)
    {
        const float4* wp = (const float4*)wqk;
        #pragma unroll
        for (int k = 0; k < 4; ++k) {
            float4 v = wp[t*4 + k];
            wl[t*16 + k*4 + 0] = v.x; wl[t*16 + k*4 + 1] = v.y;
            wl[t*16 + k*4 + 2] = v.z; wl[t*16 + k*4 + 3] = v.w;
        }
    }
    __syncthreads();

    float mean = sc[0], rstd = sc[1];
    int p = t >> 3, eg = t & 7;
    float acc[8];
    #pragma unroll
    for (int k = 0; k < 8; ++k) acc[k] = 0.f;
    for (int c = 0; c < 64; ++c) {
        float xv = (xs[p][c] - mean) * rstd;
        const float* wr = &wl[c*64 + eg*8];
        #pragma unroll
        for (int k = 0; k < 8; ++k) acc[k] += xv * wr[k];
    }
    float ss = 0.f;
    #pragma unroll
    for (int k = 0; k < 8; ++k) ss += acc[k]*acc[k];
    ss += __shfl_xor(ss, 1);
    ss += __shfl_xor(ss, 2);
    ss += __shfl_xor(ss, 4);
    float inv = 1.f / (sqrtf(ss) + 1e-8f);

    int xp2 = x0 + p;
    int b2 = (y & 1)*2 + (xp2 & 1);
    int nidx = (y >> 1)*64 + (xp2 >> 1);
    bf16x8 qv;
    #pragma unroll
    for (int k = 0; k < 8; ++k) qv[k] = (bf16)(acc[k]*inv);
    *(bf16x8*)(Q + ((size_t)b2*NQ + nidx)*64 + eg*8) = qv;
}

// ---------- K3: flash attention; S^T orientation, packed P writes, l via ones-MFMA ----------
__global__ __launch_bounds__(256, 4) void k_attn(const bf16* __restrict__ Q, const bf16* __restrict__ Vt,
                                                 bf16* __restrict__ Opart, float* __restrict__ lpart) {
    int bx = blockIdx.x;
    int b2 = bx & 3;            // XCD-friendly
    int rest = bx >> 2;
    int jq = rest & 7;          // j eighth (512 cols)
    int it = rest >> 3;         // 0..31 -> i-tile of 128 rows
    int tid = threadIdx.x;
    int w = tid >> 6, lane = tid & 63, q = lane >> 4, l15 = lane & 15;
    int ibase = it*128 + w*32;

    const bf16* Qb = Q  + (size_t)b2*NQ*64;
    const bf16* Vb = Vt + (size_t)b2*64*NQ;

    // wave's own 32 i-rows as B-fragments (n = i on lanes)
    bf16x8 aq[2][2];
    #pragma unroll
    for (int nt = 0; nt < 2; ++nt) {
        const bf16* p = Qb + (size_t)(ibase + nt*16 + l15)*64 + q*8;
        aq[nt][0] = *(const bf16x8*)p;
        aq[nt][1] = *(const bf16x8*)(p + 32);
    }
    bf16x8 ones;
    #pragma unroll
    for (int k = 0; k < 8; ++k) ones[k] = (bf16)1.0f;

    f32x4 o[2][4];
    f32x4 ol[2];
    #pragma unroll
    for (int mt = 0; mt < 2; ++mt) {
        ol[mt] = (f32x4){0.f,0.f,0.f,0.f};
        #pragma unroll
        for (int n = 0; n < 4; ++n) o[mt][n] = (f32x4){0.f,0.f,0.f,0.f};
    }

    __shared__ __align__(16) bf16 Qs[32][72];       // j-rows of Q (A for QK^T)
    __shared__ __align__(16) bf16 Vs[64][40];       // ch-major V tile (B for PV)
    __shared__ __align__(16) bf16 plds[4][32][40];  // P[i][j] per wave

    int qrow = tid >> 3, qc8 = tid & 7;
    int vch = tid >> 2, vsg = tid & 3;
    int j0 = jq * 512;
    for (int itj = 0; itj < 16; ++itj) {
        int jt = j0 + itj*32;
        __syncthreads();
        *(bf16x8*)&Qs[qrow][qc8*8] = *(const bf16x8*)(Qb + (size_t)(jt + qrow)*64 + qc8*8);
        *(bf16x8*)&Vs[vch][vsg*8]  = *(const bf16x8*)(Vb + (size_t)vch*NQ + jt + vsg*8);
        __syncthreads();

        f32x4 z = (f32x4){0.f,0.f,0.f,0.f};
        #pragma unroll
        for (int mtj = 0; mtj < 2; ++mtj) {          // j 16-block (rows of S^T)
            bf16x8 a0 = *(const bf16x8*)&Qs[mtj*16 + l15][q*8];
            bf16x8 a1 = *(const bf16x8*)&Qs[mtj*16 + l15][32 + q*8];
            #pragma unroll
            for (int nti = 0; nti < 2; ++nti) {      // i 16-block (cols of S^T)
                f32x4 s = MFMA16(a0, aq[nti][0], z);
                s = MFMA16(a1, aq[nti][1], s);
                bf16x4 pk;
                #pragma unroll
                for (int r = 0; r < 4; ++r) {
                    float sv = s[r];
                    float pv = fmaf(fmaf(fmaf(EC3, sv, EC2), sv, EC1), sv, EC0);
                    pk[r] = (bf16)pv;
                }
                *(bf16x4*)&plds[w][nti*16 + l15][mtj*16 + q*4] = pk;
            }
        }
        // PV: A = P rows (m=i), B = V^T rows (n=c); l via ones-B
        bf16x8 ap0 = *(const bf16x8*)&plds[w][l15][q*8];
        bf16x8 ap1 = *(const bf16x8*)&plds[w][16 + l15][q*8];
        ol[0] = MFMA16(ap0, ones, ol[0]);
        ol[1] = MFMA16(ap1, ones, ol[1]);
        #pragma unroll
        for (int nc = 0; nc < 4; ++nc) {
            bf16x8 bv = *(const bf16x8*)&Vs[nc*16 + l15][q*8];
            o[0][nc] = MFMA16(ap0, bv, o[0][nc]);
            o[1][nc] = MFMA16(ap1, bv, o[1][nc]);
        }
    }

    #pragma unroll
    for (int mt = 0; mt < 2; ++mt) {
        #pragma unroll
        for (int r = 0; r < 4; ++r) {
            int gr = b2*NQ + ibase + mt*16 + q*4 + r;
            bf16* orow = Opart + ((size_t)jq*16384 + gr)*64;
            #pragma unroll
            for (int nc = 0; nc < 4; ++nc) orow[nc*16 + l15] = (bf16)o[mt][nc][r];
            if (l15 == 0) lpart[(size_t)jq*16384 + gr] = ol[mt][r];
        }
    }
}

// ---------- K4: combine partials + convl (65->64, 1x1) + x  ->  T (HWC bf16) ----------
__global__ __launch_bounds__(256) void k_convl(const bf16* __restrict__ Op, const float* __restrict__ lp,
                                               const float* __restrict__ unet, const float* __restrict__ x,
                                               const float* __restrict__ wl, const float* __restrict__ bl,
                                               bf16* __restrict__ T) {
    int t = threadIdx.x, bx = blockIdx.x;
    int bxg = bx >> 1, half = bx & 1;
    int p0 = bx * 32;
    __shared__ float als[32][65];
    __shared__ float xls[32][65];
    __shared__ float wls[65*64];
    {
        int ci = t >> 2, seg = t & 3;
        int gr = ((ci >> 4) * 4096) + ((ci & 15) * 256) + bxg;
        float lsum = 0.f;
        #pragma unroll
        for (int p = 0; p < 8; ++p) lsum += lp[p*16384 + gr];
        float linv = 1.f / lsum;
        float acc[8];
        #pragma unroll
        for (int k = 0; k < 8; ++k) acc[k] = 0.f;
        #pragma unroll
        for (int p = 0; p < 8; ++p) {
            bf16x8 v = *(const bf16x8*)(Op + ((size_t)p*16384 + gr)*64 + half*32 + seg*8);
            #pragma unroll
            for (int k = 0; k < 8; ++k) acc[k] += (float)v[k];
        }
        #pragma unroll
        for (int k = 0; k < 8; ++k) als[seg*8 + k][ci] = acc[k] * linv;
        const float4* xp = (const float4*)(x + (size_t)ci*HW + p0 + seg*8);
        float4 u0 = xp[0], u1 = xp[1];
        xls[seg*8+0][ci]=u0.x; xls[seg*8+1][ci]=u0.y; xls[seg*8+2][ci]=u0.z; xls[seg*8+3][ci]=u0.w;
        xls[seg*8+4][ci]=u1.x; xls[seg*8+5][ci]=u1.y; xls[seg*8+6][ci]=u1.z; xls[seg*8+7][ci]=u1.w;
        for (int i = t; i < 65*64; i += 256) wls[i] = wl[i];
    }
    __syncthreads();

    int pg = t & 7, cg = t >> 3;   // 4 pixels, 2 out-channels each
    float acc[4][2];
    #pragma unroll
    for (int i = 0; i < 4; ++i) { acc[i][0] = 0.f; acc[i][1] = 0.f; }

    for (int ci = 0; ci < 64; ++ci) {
        float wv0 = wls[(cg*2 + 0)*65 + ci];
        float wv1 = wls[(cg*2 + 1)*65 + ci];
        #pragma unroll
        for (int i = 0; i < 4; ++i) {
            float v = als[pg*4 + i][ci];
            acc[i][0] += v * wv0;
            acc[i][1] += v * wv1;
        }
    }
    {   // unet channel (ci = 64)
        float wu0 = wls[(cg*2 + 0)*65 + 64];
        float wu1 = wls[(cg*2 + 1)*65 + 64];
        #pragma unroll
        for (int i = 0; i < 4; ++i) {
            float u = unet[p0 + pg*4 + i];
            acc[i][0] += u * wu0;
            acc[i][1] += u * wu1;
        }
    }
    #pragma unroll
    for (int i = 0; i < 4; ++i) {
        #pragma unroll
        for (int k = 0; k < 2; ++k) {
            float v = xls[pg*4 + i][cg*2 + k] + acc[i][k] + bl[cg*2 + k];
            T[(size_t)(p0 + pg*4 + i)*64 + cg*2 + k] = (bf16)v;
        }
    }
}

// ---------- K5/K6: 3x3 conv (dilation d) + bias + relu, HWC bf16 -> HWC bf16, co 4-way ----------
__global__ __launch_bounds__(256) void k_conv3x3(const bf16* __restrict__ IN, const bf16* __restrict__ WT,
                                                 const float* __restrict__ B, bf16* __restrict__ OUT,
                                                 int dil) {
    int tid = threadIdx.x, bx = blockIdx.x;
    int y = bx >> 3, xh = (bx >> 2) & 1, coq = bx & 3;
    int w = tid >> 6, lane = tid & 63, q = lane >> 4, l15 = lane & 15;
    int xb = xh*64 + w*16;
    f32x4 o = (f32x4){0.f,0.f,0.f,0.f};

    #pragma unroll
    for (int ky = 0; ky < 3; ++ky) {
        int yy = y + (ky - 1)*dil;
        bool yok = (yy >= 0) && (yy < 128);
        #pragma unroll
        for (int kx = 0; kx < 3; ++kx) {
            int xx = xb + l15 + (kx - 1)*dil;
            bool ok = yok && (xx >= 0) && (xx < 128);
            bf16x8 alo = {}, ahi = {};
            if (ok) {
                const bf16* ip = IN + (size_t)(yy*128 + xx)*64 + q*8;
                alo = *(const bf16x8*)ip;
                ahi = *(const bf16x8*)(ip + 32);
            }
            int tap = ky*3 + kx;
            const bf16* wp = WT + (size_t)(tap*64 + coq*16 + l15)*64 + q*8;
            bf16x8 blo = *(const bf16x8*)wp;
            bf16x8 bhi = *(const bf16x8*)(wp + 32);
            o = MFMA16(alo, blo, o);
            o = MFMA16(ahi, bhi, o);
        }
    }
    int co = coq*16 + l15;
    float bias = B[co];
    #pragma unroll
    for (int r = 0; r < 4; ++r) {
        float v = o[r] + bias;
        v = fmaxf(v, 0.f);
        OUT[(size_t)(y*128 + xb + q*4 + r)*64 + co] = (bf16)v;
    }
}

// ---------- K7: conv3 1x1 + bias + x -> d_out (CHW fp32), co 2-way ----------
__global__ __launch_bounds__(256) void k_conv3(const bf16* __restrict__ T3, const bf16* __restrict__ W3,
                                               const float* __restrict__ b3, const float* __restrict__ x,
                                               float* __restrict__ out) {
    int tid = threadIdx.x, bx = blockIdx.x;
    int pg = bx >> 1, coh = bx & 1;
    int w = tid >> 6, lane = tid & 63, q = lane >> 4, l15 = lane & 15;
    int p0 = pg*64 + w*16;
    const bf16* bp = T3 + (size_t)(p0 + l15)*64 + q*8;
    bf16x8 blo = *(const bf16x8*)bp;
    bf16x8 bhi = *(const bf16x8*)(bp + 32);
    f32x4 z = (f32x4){0.f,0.f,0.f,0.f};
    f32x4 o[2];
    #pragma unroll
    for (int mt = 0; mt < 2; ++mt) {
        const bf16* ap = W3 + (size_t)(coh*32 + mt*16 + l15)*64 + q*8;
        bf16x8 alo = *(const bf16x8*)ap;
        bf16x8 ahi = *(const bf16x8*)(ap + 32);
        f32x4 s = MFMA16(alo, blo, z);
        o[mt] = MFMA16(ahi, bhi, s);
    }
    #pragma unroll
    for (int mt = 0; mt < 2; ++mt) {
        #pragma unroll
        for (int r = 0; r < 4; ++r) {
            int co = coh*32 + mt*16 + q*4 + r;
            size_t idx = (size_t)co*HW + p0 + l15;
            out[idx] = x[idx] + b3[co] + o[mt][r];
        }
    }
}

extern "C" void kernel_launch(void* const* d_in, const int* in_sizes, int n_in,
                              void* d_out, int out_size, void* d_ws, size_t ws_size,
                              hipStream_t stream) {
    (void)in_sizes; (void)n_in; (void)out_size; (void)ws_size;
    const float* x    = (const float*)d_in[0];
    const float* unet = (const float*)d_in[1];
    const float* wqk  = (const float*)d_in[2];
    const float* c1w  = (const float*)d_in[3];
    const float* c1b  = (const float*)d_in[4];
    const float* c2w  = (const float*)d_in[5];
    const float* c2b  = (const float*)d_in[6];
    const float* c3w  = (const float*)d_in[7];
    const float* c3b  = (const float*)d_in[8];
    const float* clw  = (const float*)d_in[9];
    const float* clb  = (const float*)d_in[10];
    float* out = (float*)d_out;

    char* ws = (char*)d_ws;
    float* red   = (float*)(ws + OFF_RED);
    bf16*  Q     = (bf16*)(ws + OFF_Q);
    bf16*  Vt    = (bf16*)(ws + OFF_VT);
    bf16*  Opart = (bf16*)(ws + OFF_OP);
    float* lpart = (float*)(ws + OFF_LP);
    bf16*  T     = (bf16*)(ws + OFF_T);
    bf16*  T2    = (bf16*)(ws + OFF_T2);
    bf16*  T3    = (bf16*)(ws + OFF_T3);
    bf16*  W1    = (bf16*)(ws + OFF_W1);
    bf16*  W2    = (bf16*)(ws + OFF_W2);
    bf16*  W3    = (bf16*)(ws + OFF_W3);

    k_red1w<<<dim3(560), dim3(256), 0, stream>>>(x, red, c1w, c2w, c3w, W1, W2, W3);
    k_qv<<<dim3(512),    dim3(256), 0, stream>>>(x, wqk, red, Q, Vt);
    k_attn<<<dim3(1024), dim3(256), 0, stream>>>(Q, Vt, Opart, lpart);
    k_convl<<<dim3(512), dim3(256), 0, stream>>>(Opart, lpart, unet, x, clw, clb, T);
    k_conv3x3<<<dim3(1024), dim3(256), 0, stream>>>(T,  W1, c1b, T2, 1);
    k_conv3x3<<<dim3(1024), dim3(256), 0, stream>>>(T2, W2, c2b, T3, 2);
    k_conv3<<<dim3(512), dim3(256), 0, stream>>>(T3, W3, c3b, x, out);
}

// Round 4
// 142.981 us; speedup vs baseline: 1.3461x; 1.1426x over previous
//
#include <hip/hip_runtime.h>

typedef __bf16 bf16;
typedef bf16 bf16x8 __attribute__((ext_vector_type(8)));
typedef bf16 bf16x4 __attribute__((ext_vector_type(4)));
typedef float f32x4 __attribute__((ext_vector_type(4)));

#define MFMA16(a,b,c) __builtin_amdgcn_mfma_f32_16x16x32_bf16(a,b,c,0,0,0)

#define HW 16384   // 128*128
#define NQ 4096    // positions per window

// ---- workspace layout (bytes) ----
constexpr size_t OFF_RED  = 0;                                 // 1 KB sums
constexpr size_t OFF_Q    = 4096;                              // bf16 (4,4096,64)  2 MB
constexpr size_t OFF_VT   = OFF_Q  + (size_t)2097152;          // bf16 (4,64,4096)  2 MB
constexpr size_t OFF_OP   = OFF_VT + (size_t)2097152;          // bf16 (8,16384,64) 16 MB
constexpr size_t OFF_LP   = OFF_OP + (size_t)16777216;         // fp32 (8,16384)  512 KB
constexpr size_t OFF_T    = OFF_LP + (size_t)524288;           // bf16 HWC 2 MB
constexpr size_t OFF_T2   = OFF_OP;                            // alias OP (dead after k_convl)
constexpr size_t OFF_T3   = OFF_OP + (size_t)2097152;
constexpr size_t OFF_W1   = OFF_T  + (size_t)2097152;          // bf16 (9,64,64)
constexpr size_t OFF_W2   = OFF_W1 + 73728;
constexpr size_t OFF_W3   = OFF_W2 + 73728;                    // bf16 (64,64)
constexpr size_t OFF_WL   = OFF_W3 + 8192;                     // bf16 (64,64) convl wqk part

// exp((s+1)/8) for s in [-1,1]: deg-3, coeffs e^{1/8}/(8^k k!), max err ~1.2e-5
#define EC0 1.13314845f
#define EC1 0.141643556f
#define EC2 0.0088527222f
#define EC3 3.6886342e-4f

// ---------- K0: LN sum partials (bx<256) + weight prep (bx>=256) ----------
__global__ __launch_bounds__(256) void k_red1w(const float* __restrict__ x, float* __restrict__ red,
                                               const float* __restrict__ w1, const float* __restrict__ w2,
                                               const float* __restrict__ w3, const float* __restrict__ wlc,
                                               bf16* __restrict__ W1, bf16* __restrict__ W2,
                                               bf16* __restrict__ W3, bf16* __restrict__ WLb) {
    int t = threadIdx.x, bx = blockIdx.x;
    if (bx >= 256) {
        int g = (bx - 256) * 256 + t;
        if (g < 36864) {
            int tap = g >> 12, co = (g >> 6) & 63, ci = g & 63;
            W1[g] = (bf16)w1[(co*64 + ci)*9 + tap];
        } else if (g < 73728) {
            int d = g - 36864;
            int tap = d >> 12, co = (d >> 6) & 63, ci = d & 63;
            W2[d] = (bf16)w2[(co*64 + ci)*9 + tap];
        } else if (g < 77824) {
            int d = g - 73728;
            W3[d] = (bf16)w3[d];
        } else if (g < 81920) {
            int d = g - 77824;
            WLb[d] = (bf16)wlc[(d >> 6)*65 + (d & 63)];
        }
        return;
    }
    float s = 0.f;
    const float* base = x + (size_t)bx*4096;
    #pragma unroll
    for (int k = 0; k < 4; ++k) {
        float4 v = *(const float4*)(base + k*1024 + t*4);
        s += v.x + v.y + v.z + v.w;
    }
    __shared__ float rs[256];
    rs[t] = s; __syncthreads();
    for (int off = 128; off; off >>= 1) {
        if (t < off) rs[t] += rs[t+off];
        __syncthreads();
    }
    if (t == 0) red[bx] = rs[0];
}

// ---------- K2: Q = normalize(x@wqk - mean*colsum(wqk)), Vt = x windows [bf16 ch-major] ----------
// (rstd cancels under normalization; mean folds into a fixed 64-vector vv)
__global__ __launch_bounds__(256) void k_qv(const float* __restrict__ x, const float* __restrict__ wqk,
                                            const float* __restrict__ red,
                                            bf16* __restrict__ Q, bf16* __restrict__ Vt) {
    int t = threadIdx.x, bx = blockIdx.x;
    int y = bx >> 2, x0 = (bx & 3) * 32;
    __shared__ float xs[32][65];
    __shared__ float wl[4096];
    __shared__ float rs[256];
    __shared__ float vv[64];

    rs[t] = red[t];
    __syncthreads();
    for (int off = 128; off; off >>= 1) {
        if (t < off) rs[t] += rs[t+off];
        __syncthreads();
    }

    // load 32 pixels x 64 channels; write Vt on the way
    {
        int c = t >> 2, seg = t & 3;
        const float4* xp = (const float4*)(x + (size_t)c*HW + y*128 + x0 + seg*8);
        float f[8];
        float4 v0 = xp[0], v1 = xp[1];
        f[0]=v0.x; f[1]=v0.y; f[2]=v0.z; f[3]=v0.w;
        f[4]=v1.x; f[5]=v1.y; f[6]=v1.z; f[7]=v1.w;
        #pragma unroll
        for (int k = 0; k < 8; ++k) xs[seg*8 + k][c] = f[k];
        int dh = y & 1;
        int base_n = (y >> 1)*64 + ((x0 + seg*8) >> 1);
        bf16* vte = Vt + ((size_t)((dh*2 + 0)*64 + c))*NQ + base_n;
        bf16* vto = Vt + ((size_t)((dh*2 + 1)*64 + c))*NQ + base_n;
        #pragma unroll
        for (int j = 0; j < 4; ++j) { vte[j] = (bf16)f[2*j]; vto[j] = (bf16)f[2*j+1]; }
    }
    // load wqk (64x64 fp32)
    {
        const float4* wp = (const float4*)wqk;
        #pragma unroll
        for (int k = 0; k < 4; ++k) {
            float4 v = wp[t*4 + k];
            wl[t*16 + k*4 + 0] = v.x; wl[t*16 + k*4 + 1] = v.y;
            wl[t*16 + k*4 + 2] = v.z; wl[t*16 + k*4 + 3] = v.w;
        }
    }
    __syncthreads();
    if (t < 64) {
        float cs = 0.f;
        for (int c = 0; c < 64; ++c) cs += wl[c*64 + t];
        vv[t] = rs[0] * (1.f/1048576.f) * cs;
    }
    __syncthreads();

    int p = t >> 3, eg = t & 7;
    float acc[8];
    #pragma unroll
    for (int k = 0; k < 8; ++k) acc[k] = 0.f;
    for (int c = 0; c < 64; ++c) {
        float xv = xs[p][c];
        const float* wr = &wl[c*64 + eg*8];
        #pragma unroll
        for (int k = 0; k < 8; ++k) acc[k] += xv * wr[k];
    }
    #pragma unroll
    for (int k = 0; k < 8; ++k) acc[k] -= vv[eg*8 + k];
    float ss = 0.f;
    #pragma unroll
    for (int k = 0; k < 8; ++k) ss += acc[k]*acc[k];
    ss += __shfl_xor(ss, 1);
    ss += __shfl_xor(ss, 2);
    ss += __shfl_xor(ss, 4);
    float inv = 1.f / (sqrtf(ss) + 1e-8f);

    int xp2 = x0 + p;
    int b2 = (y & 1)*2 + (xp2 & 1);
    int nidx = (y >> 1)*64 + (xp2 >> 1);
    bf16x8 qv;
    #pragma unroll
    for (int k = 0; k < 8; ++k) qv[k] = (bf16)(acc[k]*inv);
    *(bf16x8*)(Q + ((size_t)b2*NQ + nidx)*64 + eg*8) = qv;
}

// ---------- K3: flash attention; 64 i-rows/wave, 64-j tiles, l via ones-MFMA ----------
__global__ __launch_bounds__(256, 2) void k_attn(const bf16* __restrict__ Q, const bf16* __restrict__ Vt,
                                                 bf16* __restrict__ Opart, float* __restrict__ lpart) {
    int bx = blockIdx.x;
    int b2 = bx & 3;            // XCD-friendly
    int jq = (bx >> 2) & 7;     // j eighth (512 cols)
    int it = bx >> 5;           // 0..15 -> i-tile of 256 rows
    int tid = threadIdx.x;
    int w = tid >> 6, lane = tid & 63, q = lane >> 4, l15 = lane & 15;
    int ibase = it*256 + w*64;

    const bf16* Qb = Q  + (size_t)b2*NQ*64;
    const bf16* Vb = Vt + (size_t)b2*64*NQ;

    // wave's 64 i-rows as B-fragments (n = i on lanes)
    bf16x8 aq[4][2];
    #pragma unroll
    for (int nt = 0; nt < 4; ++nt) {
        const bf16* p = Qb + (size_t)(ibase + nt*16 + l15)*64 + q*8;
        aq[nt][0] = *(const bf16x8*)p;
        aq[nt][1] = *(const bf16x8*)(p + 32);
    }
    bf16x8 ones;
    #pragma unroll
    for (int k = 0; k < 8; ++k) ones[k] = (bf16)1.0f;

    f32x4 o[4][4];
    f32x4 ol[4];
    #pragma unroll
    for (int mt = 0; mt < 4; ++mt) {
        ol[mt] = (f32x4){0.f,0.f,0.f,0.f};
        #pragma unroll
        for (int n = 0; n < 4; ++n) o[mt][n] = (f32x4){0.f,0.f,0.f,0.f};
    }

    __shared__ __align__(16) bf16 Qs[64][72];       // j-rows of Q (A for S^T)
    __shared__ __align__(16) bf16 Vs[64][72];       // ch-major V tile
    __shared__ __align__(16) bf16 plds[4][64][72];  // per-wave P[i][j]

    int srow = tid >> 2, scol = (tid & 3) * 16;
    int j0 = jq * 512;
    for (int itj = 0; itj < 8; ++itj) {
        int jt = j0 + itj*64;
        __syncthreads();
        {
            const bf16* qsrc = Qb + (size_t)(jt + srow)*64 + scol;
            *(bf16x8*)&Qs[srow][scol]     = *(const bf16x8*)qsrc;
            *(bf16x8*)&Qs[srow][scol + 8] = *(const bf16x8*)(qsrc + 8);
            const bf16* vsrc = Vb + (size_t)srow*NQ + jt + scol;
            *(bf16x8*)&Vs[srow][scol]     = *(const bf16x8*)vsrc;
            *(bf16x8*)&Vs[srow][scol + 8] = *(const bf16x8*)(vsrc + 8);
        }
        __syncthreads();

        f32x4 z = (f32x4){0.f,0.f,0.f,0.f};
        #pragma unroll
        for (int mtj = 0; mtj < 4; ++mtj) {          // j 16-block (rows of S^T)
            bf16x8 a0 = *(const bf16x8*)&Qs[mtj*16 + l15][q*8];
            bf16x8 a1 = *(const bf16x8*)&Qs[mtj*16 + l15][32 + q*8];
            #pragma unroll
            for (int nti = 0; nti < 4; ++nti) {      // i 16-block (cols of S^T)
                f32x4 s = MFMA16(a0, aq[nti][0], z);
                s = MFMA16(a1, aq[nti][1], s);
                bf16x4 pk;
                #pragma unroll
                for (int r = 0; r < 4; ++r) {
                    float sv = s[r];
                    pk[r] = (bf16)fmaf(fmaf(fmaf(EC3, sv, EC2), sv, EC1), sv, EC0);
                }
                *(bf16x4*)&plds[w][nti*16 + l15][mtj*16 + q*4] = pk;
            }
        }
        // PV over two k=32 halves of the 64-j tile
        #pragma unroll
        for (int kj = 0; kj < 2; ++kj) {
            bf16x8 ap[4], bv[4];
            #pragma unroll
            for (int mt = 0; mt < 4; ++mt)
                ap[mt] = *(const bf16x8*)&plds[w][mt*16 + l15][kj*32 + q*8];
            #pragma unroll
            for (int nc = 0; nc < 4; ++nc)
                bv[nc] = *(const bf16x8*)&Vs[nc*16 + l15][kj*32 + q*8];
            #pragma unroll
            for (int mt = 0; mt < 4; ++mt) {
                ol[mt] = MFMA16(ap[mt], ones, ol[mt]);
                #pragma unroll
                for (int nc = 0; nc < 4; ++nc)
                    o[mt][nc] = MFMA16(ap[mt], bv[nc], o[mt][nc]);
            }
        }
    }

    #pragma unroll
    for (int mt = 0; mt < 4; ++mt) {
        #pragma unroll
        for (int r = 0; r < 4; ++r) {
            int gr = b2*NQ + ibase + mt*16 + q*4 + r;
            bf16* orow = Opart + ((size_t)jq*16384 + gr)*64;
            #pragma unroll
            for (int nc = 0; nc < 4; ++nc) orow[nc*16 + l15] = (bf16)o[mt][nc][r];
            if (l15 == 0) lpart[(size_t)jq*16384 + gr] = ol[mt][r];
        }
    }
}

// ---------- K4: combine partials + convl (65->64, 1x1, MFMA) + x  ->  T (HWC bf16) ----------
__global__ __launch_bounds__(256) void k_convl(const bf16* __restrict__ Op, const float* __restrict__ lp,
                                               const float* __restrict__ unet, const float* __restrict__ x,
                                               const bf16* __restrict__ WLb, const float* __restrict__ wl,
                                               const float* __restrict__ bl, bf16* __restrict__ T) {
    int t = threadIdx.x, bx = blockIdx.x;
    int p0 = bx * 64;
    __shared__ __align__(16) bf16 As[64][72];    // [px][ci] combined attn
    {
        int ci = t >> 2, seg = t & 3;
        int gr = ((ci >> 4) << 12) + ((ci & 15) << 8) + bx;
        float lsum = 0.f;
        #pragma unroll
        for (int p = 0; p < 8; ++p) lsum += lp[p*16384 + gr];
        float linv = 1.f / lsum;
        float acc[16];
        #pragma unroll
        for (int k = 0; k < 16; ++k) acc[k] = 0.f;
        #pragma unroll
        for (int p = 0; p < 8; ++p) {
            const bf16* src = Op + ((size_t)p*16384 + gr)*64 + seg*16;
            bf16x8 v0 = *(const bf16x8*)src;
            bf16x8 v1 = *(const bf16x8*)(src + 8);
            #pragma unroll
            for (int k = 0; k < 8; ++k) { acc[k] += (float)v0[k]; acc[8+k] += (float)v1[k]; }
        }
        #pragma unroll
        for (int k = 0; k < 16; ++k) As[seg*16 + k][ci] = (bf16)(acc[k] * linv);
    }
    __syncthreads();

    int w = t >> 6, lane = t & 63, q = lane >> 4, l15 = lane & 15;
    int co = w*16 + l15;
    const bf16* wp = WLb + co*64 + q*8;
    bf16x8 b0 = *(const bf16x8*)wp;
    bf16x8 b1 = *(const bf16x8*)(wp + 32);
    f32x4 z = (f32x4){0.f,0.f,0.f,0.f};
    f32x4 o[4];
    #pragma unroll
    for (int mt = 0; mt < 4; ++mt) {
        bf16x8 a0 = *(const bf16x8*)&As[mt*16 + l15][q*8];
        bf16x8 a1 = *(const bf16x8*)&As[mt*16 + l15][32 + q*8];
        f32x4 s = MFMA16(a0, b0, z);
        o[mt] = MFMA16(a1, b1, s);
    }
    float wlu = wl[co*65 + 64];
    float bias = bl[co];
    #pragma unroll
    for (int mt = 0; mt < 4; ++mt) {
        int pb = p0 + mt*16 + q*4;
        float4 un  = *(const float4*)(unet + pb);
        float4 xs4 = *(const float4*)(x + (size_t)co*HW + pb);
        float xv[4] = {xs4.x, xs4.y, xs4.z, xs4.w};
        float uv[4] = {un.x, un.y, un.z, un.w};
        #pragma unroll
        for (int r = 0; r < 4; ++r) {
            float v = o[mt][r] + uv[r]*wlu + bias + xv[r];
            T[(size_t)(pb + r)*64 + co] = (bf16)v;
        }
    }
}

// ---------- K5/K6: 3x3 conv (dilation d) + bias + relu, HWC bf16 -> HWC bf16, co 4-way, LDS weights ----------
__global__ __launch_bounds__(256) void k_conv3x3(const bf16* __restrict__ IN, const bf16* __restrict__ WT,
                                                 const float* __restrict__ B, bf16* __restrict__ OUT,
                                                 int dil) {
    int tid = threadIdx.x, bx = blockIdx.x;
    int y = bx >> 3, xh = (bx >> 2) & 1, coq = bx & 3;
    int w = tid >> 6, lane = tid & 63, q = lane >> 4, l15 = lane & 15;
    int xb = xh*64 + w*16;

    __shared__ __align__(16) bf16 wsl[9][16][72];
    for (int i = tid; i < 1152; i += 256) {
        int tap = i >> 7, rem = i & 127, co = rem >> 3, k8 = (rem & 7) * 8;
        *(bf16x8*)&wsl[tap][co][k8] =
            *(const bf16x8*)(WT + (((size_t)(tap*64 + coq*16 + co)) << 6) + k8);
    }
    __syncthreads();

    f32x4 o = (f32x4){0.f,0.f,0.f,0.f};
    #pragma unroll
    for (int ky = 0; ky < 3; ++ky) {
        int yy = y + (ky - 1)*dil;
        bool yok = (yy >= 0) && (yy < 128);
        #pragma unroll
        for (int kx = 0; kx < 3; ++kx) {
            int xx = xb + l15 + (kx - 1)*dil;
            bool ok = yok && (xx >= 0) && (xx < 128);
            bf16x8 alo = {}, ahi = {};
            if (ok) {
                const bf16* ip = IN + (size_t)(yy*128 + xx)*64 + q*8;
                alo = *(const bf16x8*)ip;
                ahi = *(const bf16x8*)(ip + 32);
            }
            int tap = ky*3 + kx;
            bf16x8 blo = *(const bf16x8*)&wsl[tap][l15][q*8];
            bf16x8 bhi = *(const bf16x8*)&wsl[tap][l15][32 + q*8];
            o = MFMA16(alo, blo, o);
            o = MFMA16(ahi, bhi, o);
        }
    }
    int co = coq*16 + l15;
    float bias = B[co];
    #pragma unroll
    for (int r = 0; r < 4; ++r) {
        float v = fmaxf(o[r] + bias, 0.f);
        OUT[(size_t)(y*128 + xb + q*4 + r)*64 + co] = (bf16)v;
    }
}

// ---------- K7: conv3 1x1 + bias + x -> d_out (CHW fp32), co 2-way ----------
__global__ __launch_bounds__(256) void k_conv3(const bf16* __restrict__ T3, const bf16* __restrict__ W3,
                                               const float* __restrict__ b3, const float* __restrict__ x,
                                               float* __restrict__ out) {
    int tid = threadIdx.x, bx = blockIdx.x;
    int pg = bx >> 1, coh = bx & 1;
    int w = tid >> 6, lane = tid & 63, q = lane >> 4, l15 = lane & 15;
    int p0 = pg*64 + w*16;
    const bf16* bp = T3 + (size_t)(p0 + l15)*64 + q*8;
    bf16x8 blo = *(const bf16x8*)bp;
    bf16x8 bhi = *(const bf16x8*)(bp + 32);
    f32x4 z = (f32x4){0.f,0.f,0.f,0.f};
    f32x4 o[2];
    #pragma unroll
    for (int mt = 0; mt < 2; ++mt) {
        const bf16* ap = W3 + (size_t)(coh*32 + mt*16 + l15)*64 + q*8;
        bf16x8 alo = *(const bf16x8*)ap;
        bf16x8 ahi = *(const bf16x8*)(ap + 32);
        f32x4 s = MFMA16(alo, blo, z);
        o[mt] = MFMA16(ahi, bhi, s);
    }
    #pragma unroll
    for (int mt = 0; mt < 2; ++mt) {
        #pragma unroll
        for (int r = 0; r < 4; ++r) {
            int co = coh*32 + mt*16 + q*4 + r;
            size_t idx = (size_t)co*HW + p0 + l15;
            out[idx] = x[idx] + b3[co] + o[mt][r];
        }
    }
}

extern "C" void kernel_launch(void* const* d_in, const int* in_sizes, int n_in,
                              void* d_out, int out_size, void* d_ws, size_t ws_size,
                              hipStream_t stream) {
    (void)in_sizes; (void)n_in; (void)out_size; (void)ws_size;
    const float* x    = (const float*)d_in[0];
    const float* unet = (const float*)d_in[1];
    const float* wqk  = (const float*)d_in[2];
    const float* c1w  = (const float*)d_in[3];
    const float* c1b  = (const float*)d_in[4];
    const float* c2w  = (const float*)d_in[5];
    const float* c2b  = (const float*)d_in[6];
    const float* c3w  = (const float*)d_in[7];
    const float* c3b  = (const float*)d_in[8];
    const float* clw  = (const float*)d_in[9];
    const float* clb  = (const float*)d_in[10];
    float* out = (float*)d_out;

    char* ws = (char*)d_ws;
    float* red   = (float*)(ws + OFF_RED);
    bf16*  Q     = (bf16*)(ws + OFF_Q);
    bf16*  Vt    = (bf16*)(ws + OFF_VT);
    bf16*  Opart = (bf16*)(ws + OFF_OP);
    float* lpart = (float*)(ws + OFF_LP);
    bf16*  T     = (bf16*)(ws + OFF_T);
    bf16*  T2    = (bf16*)(ws + OFF_T2);
    bf16*  T3    = (bf16*)(ws + OFF_T3);
    bf16*  W1    = (bf16*)(ws + OFF_W1);
    bf16*  W2    = (bf16*)(ws + OFF_W2);
    bf16*  W3    = (bf16*)(ws + OFF_W3);
    bf16*  WLb   = (bf16*)(ws + OFF_WL);

    k_red1w<<<dim3(576), dim3(256), 0, stream>>>(x, red, c1w, c2w, c3w, clw, W1, W2, W3, WLb);
    k_qv<<<dim3(512),    dim3(256), 0, stream>>>(x, wqk, red, Q, Vt);
    k_attn<<<dim3(512),  dim3(256), 0, stream>>>(Q, Vt, Opart, lpart);
    k_convl<<<dim3(256), dim3(256), 0, stream>>>(Opart, lpart, unet, x, WLb, clw, clb, T);
    k_conv3x3<<<dim3(1024), dim3(256), 0, stream>>>(T,  W1, c1b, T2, 1);
    k_conv3x3<<<dim3(1024), dim3(256), 0, stream>>>(T2, W2, c2b, T3, 2);
    k_conv3<<<dim3(512), dim3(256), 0, stream>>>(T3, W3, c3b, x, out);
}